// Round 2
// baseline (7854.869 us; speedup 1.0000x reference)
//
#include <hip/hip_runtime.h>

#define K_CB 1024
#define D_EMB 256
#define DECAY_F 0.900009f
#define OMD_F 0.099991f
#define EPS_VQ 1e-5f

#define BM 128
#define BN 128
#define BD 32
#define LDST 36
#define MAX_FLAG 65536
#define GAP_TAU 3e-4f

// ===== numpy float32 pairwise sum-of-squares emulation (exact) =====
__device__ __forceinline__ float np_block128_sq(const float* p) {
  float r[8];
#pragma unroll
  for (int j = 0; j < 8; ++j) r[j] = __fmul_rn(p[j], p[j]);
  for (int i = 8; i < 128; i += 8) {
#pragma unroll
    for (int j = 0; j < 8; ++j)
      r[j] = __fadd_rn(r[j], __fmul_rn(p[i + j], p[i + j]));
  }
  return __fadd_rn(__fadd_rn(__fadd_rn(r[0], r[1]), __fadd_rn(r[2], r[3])),
                   __fadd_rn(__fadd_rn(r[4], r[5]), __fadd_rn(r[6], r[7])));
}
__device__ __forceinline__ float np_sumsq_256(const float* p) {
  return __fadd_rn(np_block128_sq(p), np_block128_sq(p + 128));
}

// ---------------- ||w_k||^2 with numpy-exact rounding ----------------
__global__ __launch_bounds__(256) void vq_wsq_np(const float* __restrict__ w,
                                                 float* __restrict__ Cnp) {
  int k = blockIdx.x * 256 + threadIdx.x;
  if (k < K_CB) Cnp[k] = np_sumsq_256(w + (size_t)k * D_EMB);
}

// ---------------- screening pass: fp32 tiled GEMM argmin + ambiguity flag ----------------
__global__ __launch_bounds__(256) void vq_assign(
    const float* __restrict__ x, const float* __restrict__ w,
    const float* __restrict__ wsq, int* __restrict__ indices,
    int* __restrict__ flagged, int* __restrict__ flag_count) {
  __shared__ float xs[BM * LDST];
  __shared__ float wsh[BN * LDST];
  const int t  = threadIdx.x;
  const int tr = t >> 4;
  const int tc = t & 15;
  const int mb = blockIdx.x * BM;

  float bd[8], bd2[8];
  int   bi[8];
#pragma unroll
  for (int i = 0; i < 8; ++i) { bd[i] = 3.4e38f; bd2[i] = 3.4e38f; bi[i] = 0; }

  for (int kb = 0; kb < K_CB; kb += BN) {
    float acc[8][8];
#pragma unroll
    for (int i = 0; i < 8; ++i)
#pragma unroll
      for (int j = 0; j < 8; ++j) acc[i][j] = 0.f;

    for (int db = 0; db < D_EMB; db += BD) {
      __syncthreads();
#pragma unroll
      for (int l = 0; l < 4; ++l) {
        int e  = t + l * 256;
        int r  = e >> 3;
        int c4 = e & 7;
        *(float4*)(xs  + r * LDST + c4 * 4) =
            *(const float4*)(x + (size_t)(mb + r) * D_EMB + db + c4 * 4);
        *(float4*)(wsh + r * LDST + c4 * 4) =
            *(const float4*)(w + (size_t)(kb + r) * D_EMB + db + c4 * 4);
      }
      __syncthreads();
#pragma unroll
      for (int d4 = 0; d4 < BD / 4; ++d4) {
        float4 xv[8], wv[8];
#pragma unroll
        for (int i = 0; i < 8; ++i)
          xv[i] = *(const float4*)(xs + (tr + 16 * i) * LDST + d4 * 4);
#pragma unroll
        for (int j = 0; j < 8; ++j)
          wv[j] = *(const float4*)(wsh + (tc + 16 * j) * LDST + d4 * 4);
#pragma unroll
        for (int i = 0; i < 8; ++i)
#pragma unroll
          for (int j = 0; j < 8; ++j)
            acc[i][j] += xv[i].x * wv[j].x + xv[i].y * wv[j].y +
                         xv[i].z * wv[j].z + xv[i].w * wv[j].w;
      }
    }
#pragma unroll
    for (int j = 0; j < 8; ++j) {
      int   k  = kb + tc + 16 * j;
      float wq = wsq[k];
#pragma unroll
      for (int i = 0; i < 8; ++i) {
        float d = wq - 2.0f * acc[i][j];
        if (d < bd[i]) { bd2[i] = bd[i]; bd[i] = d; bi[i] = k; }
        else if (d < bd2[i]) bd2[i] = d;
      }
    }
  }

#pragma unroll
  for (int i = 0; i < 8; ++i) {
    float b = bd[i], b2 = bd2[i];
    int   ix = bi[i];
#pragma unroll
    for (int off = 1; off < 16; off <<= 1) {
      float ob  = __shfl_xor(b, off, 64);
      float ob2 = __shfl_xor(b2, off, 64);
      int   oix = __shfl_xor(ix, off, 64);
      float lo = fminf(b, ob), hi = fmaxf(b, ob);
      float n2 = fminf(fminf(b2, ob2), hi);
      int   nix = (ob < b || (ob == b && oix < ix)) ? oix : ix;
      b = lo; b2 = n2; ix = nix;
    }
    if (tc == 0) {
      int row = mb + tr + 16 * i;
      indices[row] = ix;
      if (b2 - b < GAP_TAU) {
        int p = atomicAdd(flag_count, 1);
        if (p < MAX_FLAG) flagged[p] = row;
      }
    }
  }
}

// ---------------- numpy-fp32-exact re-argmin for flagged rows ----------------
// d_np[k] = fl32( fl32(sumsq_x - fl32(2*B_k)) + sumsq_w[k] ),
// B_k = sequential fp32 FMA chain over d (OpenBLAS sgemm microkernel semantics)
__global__ __launch_bounds__(256) void vq_refine_np(
    const float* __restrict__ x, const float* __restrict__ w,
    const float* __restrict__ Cnp, const int* __restrict__ flagged,
    const int* __restrict__ flag_count, int* __restrict__ indices) {
  __shared__ float xr[8][D_EMB];
  __shared__ float Ash[8];
  const int t = threadIdx.x;
  int nf = *flag_count;
  if (nf > MAX_FLAG) nf = MAX_FLAG;
  int nblk = (nf + 7) >> 3;
  for (int bi = blockIdx.x; bi < nblk; bi += gridDim.x) {
    int base = bi * 8;
    int nr = nf - base; if (nr > 8) nr = 8;
    __syncthreads();                 // xr safe to overwrite
    for (int r = 0; r < nr; ++r)
      xr[r][t] = x[(size_t)flagged[base + r] * D_EMB + t];
    __syncthreads();
    if (t < nr) Ash[t] = np_sumsq_256(xr[t]);
    __syncthreads();

    const int rl = t >> 5;           // row within the 8-batch
    const int ln = t & 31;           // 32 lanes per row
    float bd = 3.4e38f;
    int   bik = 0x7fffffff;
    if (rl < nr) {
      float A = Ash[rl];
      const float* xp = xr[rl];
      for (int j = 0; j < 32; ++j) {
        int k = ln + (j << 5);       // per-thread ascending k
        const float* wr = w + (size_t)k * D_EMB;
        float B = 0.f;
#pragma unroll 8
        for (int d = 0; d < D_EMB; ++d) B = __fmaf_rn(xp[d], wr[d], B);
        float dq = __fadd_rn(__fsub_rn(A, __fmul_rn(2.0f, B)), Cnp[k]);
        if (dq < bd) { bd = dq; bik = k; }
        else if (dq == bd && k < bik) bik = k;
      }
    }
    // lexicographic (d, k) reduce over the 32 lanes of this row
#pragma unroll
    for (int off = 1; off < 32; off <<= 1) {
      float od = __shfl_xor(bd, off, 64);
      int   ok = __shfl_xor(bik, off, 64);
      if (od < bd || (od == bd && ok < bik)) { bd = od; bik = ok; }
    }
    if (ln == 0 && rl < nr) indices[flagged[base + rl]] = bik;
  }
}

// ---------------- gather q, commitment loss partials, EMA scatter ----------------
__global__ __launch_bounds__(256) void vq_scatter(
    const float* __restrict__ x, const float* __restrict__ w,
    const int* __restrict__ indices, float* __restrict__ q_out,
    float* __restrict__ emb_sum, float* __restrict__ counts,
    float* __restrict__ loss_part, int M) {
  __shared__ float lsum[4];
  int wib  = threadIdx.x >> 6;
  int row  = blockIdx.x * 4 + wib;
  int lane = threadIdx.x & 63;
  float s = 0.0f;
  if (row < M) {
    int idx = indices[row];
    float4 xv = *(const float4*)(x + (size_t)row * D_EMB + lane * 4);
    float4 wv = *(const float4*)(w + (size_t)idx * D_EMB + lane * 4);
    float4 qs;
    qs.x = xv.x + (wv.x - xv.x);
    qs.y = xv.y + (wv.y - xv.y);
    qs.z = xv.z + (wv.z - xv.z);
    qs.w = xv.w + (wv.w - xv.w);
    *(float4*)(q_out + (size_t)row * D_EMB + lane * 4) = qs;
    float d0 = xv.x - wv.x, d1 = xv.y - wv.y, d2 = xv.z - wv.z, d3 = xv.w - wv.w;
    s = d0 * d0 + d1 * d1 + d2 * d2 + d3 * d3;
    float* es = emb_sum + (size_t)idx * D_EMB + lane * 4;
    atomicAdd(es + 0, xv.x);
    atomicAdd(es + 1, xv.y);
    atomicAdd(es + 2, xv.z);
    atomicAdd(es + 3, xv.w);
    if (lane == 0) atomicAdd(counts + idx, 1.0f);
  }
#pragma unroll
  for (int off = 32; off >= 1; off >>= 1) s += __shfl_xor(s, off, 64);
  if (lane == 0) lsum[wib] = s;
  __syncthreads();
  if (threadIdx.x == 0)
    loss_part[blockIdx.x] = lsum[0] + lsum[1] + lsum[2] + lsum[3];
}

// ---------------- cluster-size EMA, n, norm, loss ----------------
__global__ __launch_bounds__(1024) void vq_fin_cs(
    const float* __restrict__ ema_cs, const float* __restrict__ counts,
    const float* __restrict__ loss_part, int n_part, float inv_MD,
    float* __restrict__ out_ncs, float* __restrict__ out_loss,
    float* __restrict__ norm_inv) {
  __shared__ float sm[1024];
  __shared__ float sl[1024];
  int k = threadIdx.x;
  float ncs = ema_cs[k] * DECAY_F + counts[k] * OMD_F;
  out_ncs[k] = ncs;
  float ls = 0.f;
  for (int i = k; i < n_part; i += 1024) ls += loss_part[i];
  sm[k] = ncs; sl[k] = ls;
  __syncthreads();
  for (int s2 = 512; s2 > 0; s2 >>= 1) {
    if (k < s2) { sm[k] += sm[k + s2]; sl[k] += sl[k + s2]; }
    __syncthreads();
  }
  float n = sm[0];
  norm_inv[k] = (n + (float)K_CB * EPS_VQ) / (ncs + EPS_VQ);
  if (k == 0) out_loss[0] = sl[0] * inv_MD;
}

// ---------------- embedding EMA + new weight ----------------
__global__ __launch_bounds__(256) void vq_fin_w(
    const float* __restrict__ ema_emb, const float* __restrict__ emb_sum,
    const float* __restrict__ norm_inv, float* __restrict__ out_w,
    float* __restrict__ out_emb) {
  int e = blockIdx.x * 256 + threadIdx.x;
  float4 ee = ((const float4*)ema_emb)[e];
  float4 es = ((const float4*)emb_sum)[e];
  float4 ne;
  ne.x = ee.x * DECAY_F + es.x * OMD_F;
  ne.y = ee.y * DECAY_F + es.y * OMD_F;
  ne.z = ee.z * DECAY_F + es.z * OMD_F;
  ne.w = ee.w * DECAY_F + es.w * OMD_F;
  ((float4*)out_emb)[e] = ne;
  float ni = norm_inv[e >> 6];
  float4 nw;
  nw.x = ne.x * ni; nw.y = ne.y * ni; nw.z = ne.z * ni; nw.w = ne.w * ni;
  ((float4*)out_w)[e] = nw;
}

extern "C" void kernel_launch(void* const* d_in, const int* in_sizes, int n_in,
                              void* d_out, int out_size, void* d_ws, size_t ws_size,
                              hipStream_t stream) {
  const float* x       = (const float*)d_in[0];
  const float* w       = (const float*)d_in[1];
  const float* ema_cs  = (const float*)d_in[2];
  const float* ema_emb = (const float*)d_in[3];
  const int M = in_sizes[0] / D_EMB;   // 131072

  float* out      = (float*)d_out;
  float* out_q    = out;
  float* out_loss = out + (size_t)M * D_EMB;
  float* out_w    = out_loss + 1;
  float* out_ncs  = out_w + (size_t)K_CB * D_EMB;
  float* out_emb  = out_ncs + K_CB;

  float* ws        = (float*)d_ws;
  float* Cnp       = ws;                          // K (numpy-exact ||w||^2)
  float* counts    = Cnp + K_CB;                  // K
  float* norm_inv  = counts + K_CB;               // K
  float* emb_sum   = norm_inv + K_CB;             // K*D
  int*   indices   = (int*)(emb_sum + (size_t)K_CB * D_EMB);  // M
  float* loss_part = (float*)(indices + M);       // M/4
  int*   flagged   = (int*)(loss_part + M / 4);   // MAX_FLAG
  int*   flag_count = flagged + MAX_FLAG;         // 1

  hipMemsetAsync(counts, 0, K_CB * sizeof(float), stream);
  hipMemsetAsync(emb_sum, 0, (size_t)K_CB * D_EMB * sizeof(float), stream);
  hipMemsetAsync(flag_count, 0, sizeof(int), stream);

  vq_wsq_np<<<K_CB / 256, 256, 0, stream>>>(w, Cnp);
  vq_assign<<<M / BM, 256, 0, stream>>>(x, w, Cnp, indices, flagged, flag_count);
  vq_refine_np<<<1024, 256, 0, stream>>>(x, w, Cnp, flagged, flag_count, indices);
  vq_scatter<<<M / 4, 256, 0, stream>>>(x, w, indices, out_q, emb_sum, counts,
                                        loss_part, M);
  vq_fin_cs<<<1, 1024, 0, stream>>>(ema_cs, counts, loss_part, M / 4,
                                    1.0f / ((float)M * (float)D_EMB),
                                    out_ncs, out_loss, norm_inv);
  vq_fin_w<<<K_CB * D_EMB / 4 / 256, 256, 0, stream>>>(ema_emb, emb_sum, norm_inv,
                                                       out_w, out_emb);
}

// Round 4
// 2356.544 us; speedup vs baseline: 3.3332x; 3.3332x over previous
//
#include <hip/hip_runtime.h>

#define K_CB 1024
#define D_EMB 256
#define KDIM 512                 // stored bf16-split K: [hi(256) | lo(256)]
#define DECAY_F 0.900009f
#define OMD_F 0.099991f
#define EPS_VQ 1e-5f
#define MAX_FLAG 65536
#define GAP_TAU 3e-4f

typedef __bf16 bf16x8 __attribute__((ext_vector_type(8)));
typedef float f32x4 __attribute__((ext_vector_type(4)));

__device__ __forceinline__ unsigned short bf16rn(float f) {
  unsigned u = __float_as_uint(f);
  return (unsigned short)((u + 0x7fffu + ((u >> 16) & 1u)) >> 16);
}

#define STAGE16(srcp, dstp)                                                        \
  __builtin_amdgcn_global_load_lds(                                               \
      (const __attribute__((address_space(1))) unsigned int*)(srcp),              \
      (__attribute__((address_space(3))) unsigned int*)(dstp), 16, 0, 0)

// ---------------- fp32 -> bf16 hi/lo split: dst[row] = [hi(256) | lo(256)] ----------------
__global__ __launch_bounds__(256) void vq_split(const float* __restrict__ src,
                                                unsigned short* __restrict__ dst,
                                                int nrows) {
  int g = blockIdx.x * 256 + threadIdx.x;
  int row = g >> 6, d0 = (g & 63) << 2;
  if (row >= nrows) return;
  float4 v = *(const float4*)(src + (size_t)row * D_EMB + d0);
  ushort4 hi, lo;
  hi.x = bf16rn(v.x); lo.x = bf16rn(v.x - __uint_as_float((unsigned)hi.x << 16));
  hi.y = bf16rn(v.y); lo.y = bf16rn(v.y - __uint_as_float((unsigned)hi.y << 16));
  hi.z = bf16rn(v.z); lo.z = bf16rn(v.z - __uint_as_float((unsigned)hi.z << 16));
  hi.w = bf16rn(v.w); lo.w = bf16rn(v.w - __uint_as_float((unsigned)hi.w << 16));
  *(ushort4*)(dst + (size_t)row * KDIM + d0) = hi;
  *(ushort4*)(dst + (size_t)row * KDIM + D_EMB + d0) = lo;
}

// ===== numpy float32 pairwise sum-of-squares emulation (exact) =====
__device__ __forceinline__ float np_block128_sq(const float* p) {
  float r[8];
#pragma unroll
  for (int j = 0; j < 8; ++j) r[j] = __fmul_rn(p[j], p[j]);
  for (int i = 8; i < 128; i += 8) {
#pragma unroll
    for (int j = 0; j < 8; ++j)
      r[j] = __fadd_rn(r[j], __fmul_rn(p[i + j], p[i + j]));
  }
  return __fadd_rn(__fadd_rn(__fadd_rn(r[0], r[1]), __fadd_rn(r[2], r[3])),
                   __fadd_rn(__fadd_rn(r[4], r[5]), __fadd_rn(r[6], r[7])));
}
__device__ __forceinline__ float np_sumsq_256(const float* p) {
  return __fadd_rn(np_block128_sq(p), np_block128_sq(p + 128));
}

__global__ __launch_bounds__(256) void vq_wsq_np(const float* __restrict__ w,
                                                 float* __restrict__ Cnp) {
  int k = blockIdx.x * 256 + threadIdx.x;
  if (k < K_CB) Cnp[k] = np_sumsq_256(w + (size_t)k * D_EMB);
}

// ---------------- MFMA screening GEMM + fused argmin(best/best2) ----------------
// dist = Cnp[k] - 2*<x,w_k>; dot via 3-panel bf16 split GEMM (K=768):
//   A = [x_hi | x_lo | x_hi] , B = [w_hi | w_hi | w_lo]   (drops only lo*lo ~1e-6)
// Both panels are source-offset remaps of the stored [hi|lo] K=512 buffers.
__global__ __launch_bounds__(256) void vq_gemm(
    const unsigned short* __restrict__ x2, const unsigned short* __restrict__ w2,
    const float* __restrict__ Cnp, int* __restrict__ indices,
    int* __restrict__ flagged, int* __restrict__ flag_count) {
  __shared__ unsigned short tA[128 * 64];
  __shared__ unsigned short tB[128 * 64];
  const int t = threadIdx.x;
  const int wid = t >> 6;
  const int wr = wid >> 1, wc = wid & 1;       // 2x2 wave grid, each 64(rows)x64(cols)
  const int lane = t & 63;
  const int q = lane >> 4, c = lane & 15;
  const int mb = blockIdx.x * 128;

  float b1[4][4], b2v[4][4];
  int   bi[4][4];
#pragma unroll
  for (int m = 0; m < 4; ++m)
#pragma unroll
    for (int j = 0; j < 4; ++j) { b1[m][j] = 3.4e38f; b2v[m][j] = 3.4e38f; bi[m][j] = 0; }

  for (int nt = 0; nt < 8; ++nt) {
    const int nbase = nt << 7;
    f32x4 acc[4][4];
#pragma unroll
    for (int m = 0; m < 4; ++m)
#pragma unroll
      for (int n = 0; n < 4; ++n) acc[m][n] = (f32x4){0.f, 0.f, 0.f, 0.f};

    // 12 k-chunks of 64: A panels hi,hi,hi,hi, lo.., hi..; B panels hi.., hi.., lo..
    const int AOFF[12] = {0, 64, 128, 192, 256, 320, 384, 448, 0, 64, 128, 192};
    const int BOFF[12] = {0, 64, 128, 192, 0, 64, 128, 192, 256, 320, 384, 448};
#pragma unroll
    for (int kc = 0; kc < 12; ++kc) {
#pragma unroll
      for (int cix = 0; cix < 4; ++cix) {
        int tp = (cix << 8) + t;               // 0..1023 16B slots
        int row = tp >> 3, sl = tp & 7;
        STAGE16(x2 + (size_t)(mb + row) * KDIM + AOFF[kc] + sl * 8, &tA[tp * 8]);
        STAGE16(w2 + (size_t)(nbase + row) * KDIM + BOFF[kc] + sl * 8, &tB[tp * 8]);
      }
      __syncthreads();
      bf16x8 af[4][2], bfr[4][2];
#pragma unroll
      for (int m = 0; m < 4; ++m)
#pragma unroll
        for (int ks = 0; ks < 2; ++ks) {
          af[m][ks]  = *(const bf16x8*)&tA[(wr * 64 + m * 16 + c) * 64 + ks * 32 + q * 8];
          bfr[m][ks] = *(const bf16x8*)&tB[(wc * 64 + m * 16 + c) * 64 + ks * 32 + q * 8];
        }
#pragma unroll
      for (int m = 0; m < 4; ++m)
#pragma unroll
        for (int n = 0; n < 4; ++n) {
          acc[m][n] = __builtin_amdgcn_mfma_f32_16x16x32_bf16(af[m][0], bfr[n][0], acc[m][n], 0, 0, 0);
          acc[m][n] = __builtin_amdgcn_mfma_f32_16x16x32_bf16(af[m][1], bfr[n][1], acc[m][n], 0, 0, 0);
        }
      __syncthreads();
    }

    // fold this 128-codeword tile into running best/best2 (per wave: its 64-col half)
    float cn[4]; int ck[4];
#pragma unroll
    for (int n = 0; n < 4; ++n) { ck[n] = nbase + wc * 64 + n * 16 + c; cn[n] = Cnp[ck[n]]; }
#pragma unroll
    for (int m = 0; m < 4; ++m)
#pragma unroll
      for (int j = 0; j < 4; ++j) {
        float db = 3.4e38f, db2 = 3.4e38f; int di = 0;
#pragma unroll
        for (int n = 0; n < 4; ++n) {
          float d = __fmaf_rn(-2.0f, acc[m][n][j], cn[n]);
          if (d < db) { db2 = db; db = d; di = ck[n]; }
          else if (d < db2) db2 = d;
        }
#pragma unroll
        for (int off = 1; off < 16; off <<= 1) {   // butterfly over the 16 c-lanes
          float ob  = __shfl_xor(db, off, 64);
          float ob2 = __shfl_xor(db2, off, 64);
          int   oi  = __shfl_xor(di, off, 64);
          float lo = fminf(db, ob), hi = fmaxf(db, ob);
          db2 = fminf(fminf(db2, ob2), hi);
          di  = (ob < db || (ob == db && oi < di)) ? oi : di;
          db  = lo;
        }
        if (db < b1[m][j]) {
          b2v[m][j] = fminf(b1[m][j], db2);
          b1[m][j]  = db;
          bi[m][j]  = di;
        } else {
          b2v[m][j] = fminf(b2v[m][j], db);
        }
      }
  }

  // ---- cross-wave merge: each row is covered by waves (wr,0) and (wr,1) ----
  float* sB1 = (float*)tA;           // reuse LDS (all tA reads done)
  float* sB2 = sB1 + 128;
  int*   sBI = (int*)(sB2 + 128);
  __syncthreads();
  if (wc == 1 && c == 0) {
#pragma unroll
    for (int m = 0; m < 4; ++m)
#pragma unroll
      for (int j = 0; j < 4; ++j) {
        int r = wr * 64 + m * 16 + q * 4 + j;
        sB1[r] = b1[m][j]; sB2[r] = b2v[m][j]; sBI[r] = bi[m][j];
      }
  }
  __syncthreads();
  if (wc == 0 && c == 0) {
#pragma unroll
    for (int m = 0; m < 4; ++m)
#pragma unroll
      for (int j = 0; j < 4; ++j) {
        int r = wr * 64 + m * 16 + q * 4 + j;
        float o1 = sB1[r], o2 = sB2[r];
        int   oi = sBI[r];
        float best, sec; int bidx;
        if (o1 < b1[m][j] || (o1 == b1[m][j] && oi < bi[m][j])) {
          best = o1; bidx = oi; sec = fminf(o2, b1[m][j]);
        } else {
          best = b1[m][j]; bidx = bi[m][j]; sec = fminf(b2v[m][j], o1);
        }
        indices[mb + r] = bidx;
        if (sec - best < GAP_TAU) {
          int p = atomicAdd(flag_count, 1);
          if (p < MAX_FLAG) flagged[p] = mb + r;
        }
      }
  }
}

// ---------------- numpy-fp32-exact re-argmin for flagged rows ----------------
__global__ __launch_bounds__(256) void vq_refine_np(
    const float* __restrict__ x, const float* __restrict__ w,
    const float* __restrict__ Cnp, const int* __restrict__ flagged,
    const int* __restrict__ flag_count, int* __restrict__ indices) {
  __shared__ float xr[8][D_EMB];
  __shared__ float Ash[8];
  const int t = threadIdx.x;
  int nf = *flag_count;
  if (nf > MAX_FLAG) nf = MAX_FLAG;
  int nblk = (nf + 7) >> 3;
  for (int bi = blockIdx.x; bi < nblk; bi += gridDim.x) {
    int base = bi * 8;
    int nr = nf - base; if (nr > 8) nr = 8;
    __syncthreads();
    for (int r = 0; r < nr; ++r)
      xr[r][t] = x[(size_t)flagged[base + r] * D_EMB + t];
    __syncthreads();
    if (t < nr) Ash[t] = np_sumsq_256(xr[t]);
    __syncthreads();

    const int rl = t >> 5;
    const int ln = t & 31;
    float bd = 3.4e38f;
    int   bik = 0x7fffffff;
    if (rl < nr) {
      float A = Ash[rl];
      const float* xp = xr[rl];
      for (int j = 0; j < 32; ++j) {
        int k = ln + (j << 5);
        const float* wr = w + (size_t)k * D_EMB;
        float B = 0.f;
#pragma unroll 8
        for (int d = 0; d < D_EMB; ++d) B = __fmaf_rn(xp[d], wr[d], B);
        float dq = __fadd_rn(__fsub_rn(A, __fmul_rn(2.0f, B)), Cnp[k]);
        if (dq < bd) { bd = dq; bik = k; }
        else if (dq == bd && k < bik) bik = k;
      }
    }
#pragma unroll
    for (int off = 1; off < 32; off <<= 1) {
      float od = __shfl_xor(bd, off, 64);
      int   ok = __shfl_xor(bik, off, 64);
      if (od < bd || (od == bd && ok < bik)) { bd = od; bik = ok; }
    }
    if (ln == 0 && rl < nr) indices[flagged[base + rl]] = bik;
  }
}

// ---------------- gather q, commitment loss partials, EMA scatter ----------------
__global__ __launch_bounds__(256) void vq_scatter(
    const float* __restrict__ x, const float* __restrict__ w,
    const int* __restrict__ indices, float* __restrict__ q_out,
    float* __restrict__ emb_sum, float* __restrict__ counts,
    float* __restrict__ loss_part, int M) {
  __shared__ float lsum[4];
  int wib  = threadIdx.x >> 6;
  int row  = blockIdx.x * 4 + wib;
  int lane = threadIdx.x & 63;
  float s = 0.0f;
  if (row < M) {
    int idx = indices[row];
    float4 xv = *(const float4*)(x + (size_t)row * D_EMB + lane * 4);
    float4 wv = *(const float4*)(w + (size_t)idx * D_EMB + lane * 4);
    float4 qs;
    qs.x = xv.x + (wv.x - xv.x);
    qs.y = xv.y + (wv.y - xv.y);
    qs.z = xv.z + (wv.z - xv.z);
    qs.w = xv.w + (wv.w - xv.w);
    *(float4*)(q_out + (size_t)row * D_EMB + lane * 4) = qs;
    float d0 = xv.x - wv.x, d1 = xv.y - wv.y, d2 = xv.z - wv.z, d3 = xv.w - wv.w;
    s = d0 * d0 + d1 * d1 + d2 * d2 + d3 * d3;
    float* es = emb_sum + (size_t)idx * D_EMB + lane * 4;
    atomicAdd(es + 0, xv.x);
    atomicAdd(es + 1, xv.y);
    atomicAdd(es + 2, xv.z);
    atomicAdd(es + 3, xv.w);
    if (lane == 0) atomicAdd(counts + idx, 1.0f);
  }
#pragma unroll
  for (int off = 32; off >= 1; off >>= 1) s += __shfl_xor(s, off, 64);
  if (lane == 0) lsum[wib] = s;
  __syncthreads();
  if (threadIdx.x == 0)
    loss_part[blockIdx.x] = lsum[0] + lsum[1] + lsum[2] + lsum[3];
}

// ---------------- cluster-size EMA, n, norm, loss ----------------
__global__ __launch_bounds__(1024) void vq_fin_cs(
    const float* __restrict__ ema_cs, const float* __restrict__ counts,
    const float* __restrict__ loss_part, int n_part, float inv_MD,
    float* __restrict__ out_ncs, float* __restrict__ out_loss,
    float* __restrict__ norm_inv) {
  __shared__ float sm[1024];
  __shared__ float sl[1024];
  int k = threadIdx.x;
  float ncs = ema_cs[k] * DECAY_F + counts[k] * OMD_F;
  out_ncs[k] = ncs;
  float ls = 0.f;
  for (int i = k; i < n_part; i += 1024) ls += loss_part[i];
  sm[k] = ncs; sl[k] = ls;
  __syncthreads();
  for (int s2 = 512; s2 > 0; s2 >>= 1) {
    if (k < s2) { sm[k] += sm[k + s2]; sl[k] += sl[k + s2]; }
    __syncthreads();
  }
  float n = sm[0];
  norm_inv[k] = (n + (float)K_CB * EPS_VQ) / (ncs + EPS_VQ);
  if (k == 0) out_loss[0] = sl[0] * inv_MD;
}

// ---------------- embedding EMA + new weight ----------------
__global__ __launch_bounds__(256) void vq_fin_w(
    const float* __restrict__ ema_emb, const float* __restrict__ emb_sum,
    const float* __restrict__ norm_inv, float* __restrict__ out_w,
    float* __restrict__ out_emb) {
  int e = blockIdx.x * 256 + threadIdx.x;
  float4 ee = ((const float4*)ema_emb)[e];
  float4 es = ((const float4*)emb_sum)[e];
  float4 ne;
  ne.x = ee.x * DECAY_F + es.x * OMD_F;
  ne.y = ee.y * DECAY_F + es.y * OMD_F;
  ne.z = ee.z * DECAY_F + es.z * OMD_F;
  ne.w = ee.w * DECAY_F + es.w * OMD_F;
  ((float4*)out_emb)[e] = ne;
  float ni = norm_inv[e >> 6];
  float4 nw;
  nw.x = ne.x * ni; nw.y = ne.y * ni; nw.z = ne.z * ni; nw.w = ne.w * ni;
  ((float4*)out_w)[e] = nw;
}

extern "C" void kernel_launch(void* const* d_in, const int* in_sizes, int n_in,
                              void* d_out, int out_size, void* d_ws, size_t ws_size,
                              hipStream_t stream) {
  const float* x       = (const float*)d_in[0];
  const float* w       = (const float*)d_in[1];
  const float* ema_cs  = (const float*)d_in[2];
  const float* ema_emb = (const float*)d_in[3];
  const int M = in_sizes[0] / D_EMB;   // 131072

  float* out      = (float*)d_out;
  float* out_q    = out;
  float* out_loss = out + (size_t)M * D_EMB;
  float* out_w    = out_loss + 1;
  float* out_ncs  = out_w + (size_t)K_CB * D_EMB;
  float* out_emb  = out_ncs + K_CB;

  float* ws         = (float*)d_ws;
  float* Cnp        = ws;                                      // 1024
  float* counts     = Cnp + K_CB;                              // 1024
  float* norm_inv   = counts + K_CB;                           // 1024
  float* emb_sum    = norm_inv + K_CB;                         // K*D
  int*   indices    = (int*)(emb_sum + (size_t)K_CB * D_EMB);  // M
  float* loss_part  = (float*)(indices + M);                   // M/4
  int*   flagged    = (int*)(loss_part + M / 4);               // MAX_FLAG
  int*   flag_count = flagged + MAX_FLAG;                      // 1 (+3 pad)
  unsigned short* w2 = (unsigned short*)(flag_count + 4);      // K*KDIM bf16

  // x2 (bf16 split of x) lives in the out_q region: exactly M*512*2 bytes,
  // fully rewritten by vq_scatter afterwards.
  unsigned short* x2 = (unsigned short*)out_q;

  hipMemsetAsync(counts, 0, K_CB * sizeof(float), stream);
  hipMemsetAsync(emb_sum, 0, (size_t)K_CB * D_EMB * sizeof(float), stream);
  hipMemsetAsync(flag_count, 0, sizeof(int), stream);

  vq_split<<<M * 64 / 256, 256, 0, stream>>>(x, x2, M);
  vq_split<<<K_CB * 64 / 256, 256, 0, stream>>>(w, w2, K_CB);
  vq_wsq_np<<<K_CB / 256, 256, 0, stream>>>(w, Cnp);
  vq_gemm<<<M / 128, 256, 0, stream>>>(x2, w2, Cnp, indices, flagged, flag_count);
  vq_refine_np<<<1024, 256, 0, stream>>>(x, w, Cnp, flagged, flag_count, indices);
  vq_scatter<<<M / 4, 256, 0, stream>>>(x, w, indices, out_q, emb_sum, counts,
                                        loss_part, M);
  vq_fin_cs<<<1, 1024, 0, stream>>>(ema_cs, counts, loss_part, M / 4,
                                    1.0f / ((float)M * (float)D_EMB),
                                    out_ncs, out_loss, norm_inv);
  vq_fin_w<<<K_CB * D_EMB / 4 / 256, 256, 0, stream>>>(ema_emb, emb_sum, norm_inv,
                                                       out_w, out_emb);
}

// Round 5
// 1303.590 us; speedup vs baseline: 6.0256x; 1.8077x over previous
//
#include <hip/hip_runtime.h>

#define K_CB 1024
#define D_EMB 256
#define KDIM 512                 // stored bf16-split K: [hi(256) | lo(256)]
#define DECAY_F 0.900009f
#define OMD_F 0.099991f
#define EPS_VQ 1e-5f
#define MAX_FLAG 65536
#define GAP_TAU 3e-4f
#define RB 16                    // flagged rows per refine block

typedef __bf16 bf16x8 __attribute__((ext_vector_type(8)));
typedef float f32x4 __attribute__((ext_vector_type(4)));

__device__ __forceinline__ unsigned short bf16rn(float f) {
  unsigned u = __float_as_uint(f);
  return (unsigned short)((u + 0x7fffu + ((u >> 16) & 1u)) >> 16);
}

#define STAGE16(srcp, dstp)                                                        \
  __builtin_amdgcn_global_load_lds(                                               \
      (const __attribute__((address_space(1))) unsigned int*)(srcp),              \
      (__attribute__((address_space(3))) unsigned int*)(dstp), 16, 0, 0)

// ---------------- fp32 -> bf16 hi/lo split: dst[row] = [hi(256) | lo(256)] ----------------
__global__ __launch_bounds__(256) void vq_split(const float* __restrict__ src,
                                                unsigned short* __restrict__ dst,
                                                int nrows) {
  int g = blockIdx.x * 256 + threadIdx.x;
  int row = g >> 6, d0 = (g & 63) << 2;
  if (row >= nrows) return;
  float4 v = *(const float4*)(src + (size_t)row * D_EMB + d0);
  ushort4 hi, lo;
  hi.x = bf16rn(v.x); lo.x = bf16rn(v.x - __uint_as_float((unsigned)hi.x << 16));
  hi.y = bf16rn(v.y); lo.y = bf16rn(v.y - __uint_as_float((unsigned)hi.y << 16));
  hi.z = bf16rn(v.z); lo.z = bf16rn(v.z - __uint_as_float((unsigned)hi.z << 16));
  hi.w = bf16rn(v.w); lo.w = bf16rn(v.w - __uint_as_float((unsigned)hi.w << 16));
  *(ushort4*)(dst + (size_t)row * KDIM + d0) = hi;
  *(ushort4*)(dst + (size_t)row * KDIM + D_EMB + d0) = lo;
}

// ---------------- w transpose: wT[d][k] = w[k][d] (for coalesced refine reads) ----------------
__global__ __launch_bounds__(256) void vq_transpose(const float* __restrict__ w,
                                                    float* __restrict__ wT) {
  __shared__ float tile[64][65];
  int bk = (blockIdx.x & 15) * 64;       // k block (K=1024 -> 16)
  int bd = (blockIdx.x >> 4) * 64;       // d block (D=256  -> 4)
  for (int i = threadIdx.x; i < 64 * 16; i += 256) {
    int kk = i >> 4, dd4 = (i & 15) * 4;
    float4 v = *(const float4*)(w + (size_t)(bk + kk) * D_EMB + bd + dd4);
    tile[kk][dd4]     = v.x; tile[kk][dd4 + 1] = v.y;
    tile[kk][dd4 + 2] = v.z; tile[kk][dd4 + 3] = v.w;
  }
  __syncthreads();
  for (int i = threadIdx.x; i < 64 * 64; i += 256) {
    int dd = i >> 6, kk = i & 63;
    wT[(size_t)(bd + dd) * K_CB + bk + kk] = tile[kk][dd];
  }
}

// ===== numpy float32 pairwise sum-of-squares emulation (exact) =====
__device__ __forceinline__ float np_block128_sq(const float* p) {
  float r[8];
#pragma unroll
  for (int j = 0; j < 8; ++j) r[j] = __fmul_rn(p[j], p[j]);
  for (int i = 8; i < 128; i += 8) {
#pragma unroll
    for (int j = 0; j < 8; ++j)
      r[j] = __fadd_rn(r[j], __fmul_rn(p[i + j], p[i + j]));
  }
  return __fadd_rn(__fadd_rn(__fadd_rn(r[0], r[1]), __fadd_rn(r[2], r[3])),
                   __fadd_rn(__fadd_rn(r[4], r[5]), __fadd_rn(r[6], r[7])));
}
__device__ __forceinline__ float np_sumsq_256(const float* p) {
  return __fadd_rn(np_block128_sq(p), np_block128_sq(p + 128));
}

__global__ __launch_bounds__(256) void vq_wsq_np(const float* __restrict__ w,
                                                 float* __restrict__ Cnp) {
  int k = blockIdx.x * 256 + threadIdx.x;
  if (k < K_CB) Cnp[k] = np_sumsq_256(w + (size_t)k * D_EMB);
}

// ---------------- MFMA screening GEMM + fused argmin(best/best2) ----------------
__global__ __launch_bounds__(256) void vq_gemm(
    const unsigned short* __restrict__ x2, const unsigned short* __restrict__ w2,
    const float* __restrict__ Cnp, int* __restrict__ indices,
    int* __restrict__ flagged, int* __restrict__ flag_count) {
  __shared__ unsigned short tA[128 * 64];
  __shared__ unsigned short tB[128 * 64];
  const int t = threadIdx.x;
  const int wid = t >> 6;
  const int wr = wid >> 1, wc = wid & 1;       // 2x2 wave grid, each 64(rows)x64(cols)
  const int lane = t & 63;
  const int q = lane >> 4, c = lane & 15;
  const int mb = blockIdx.x * 128;

  float b1[4][4], b2v[4][4];
  int   bi[4][4];
#pragma unroll
  for (int m = 0; m < 4; ++m)
#pragma unroll
    for (int j = 0; j < 4; ++j) { b1[m][j] = 3.4e38f; b2v[m][j] = 3.4e38f; bi[m][j] = 0; }

  for (int nt = 0; nt < 8; ++nt) {
    const int nbase = nt << 7;
    f32x4 acc[4][4];
#pragma unroll
    for (int m = 0; m < 4; ++m)
#pragma unroll
      for (int n = 0; n < 4; ++n) acc[m][n] = (f32x4){0.f, 0.f, 0.f, 0.f};

    const int AOFF[12] = {0, 64, 128, 192, 256, 320, 384, 448, 0, 64, 128, 192};
    const int BOFF[12] = {0, 64, 128, 192, 0, 64, 128, 192, 256, 320, 384, 448};
#pragma unroll
    for (int kc = 0; kc < 12; ++kc) {
#pragma unroll
      for (int cix = 0; cix < 4; ++cix) {
        int tp = (cix << 8) + t;
        int row = tp >> 3, sl = tp & 7;
        STAGE16(x2 + (size_t)(mb + row) * KDIM + AOFF[kc] + sl * 8, &tA[tp * 8]);
        STAGE16(w2 + (size_t)(nbase + row) * KDIM + BOFF[kc] + sl * 8, &tB[tp * 8]);
      }
      __syncthreads();
      bf16x8 af[4][2], bfr[4][2];
#pragma unroll
      for (int m = 0; m < 4; ++m)
#pragma unroll
        for (int ks = 0; ks < 2; ++ks) {
          af[m][ks]  = *(const bf16x8*)&tA[(wr * 64 + m * 16 + c) * 64 + ks * 32 + q * 8];
          bfr[m][ks] = *(const bf16x8*)&tB[(wc * 64 + m * 16 + c) * 64 + ks * 32 + q * 8];
        }
#pragma unroll
      for (int m = 0; m < 4; ++m)
#pragma unroll
        for (int n = 0; n < 4; ++n) {
          acc[m][n] = __builtin_amdgcn_mfma_f32_16x16x32_bf16(af[m][0], bfr[n][0], acc[m][n], 0, 0, 0);
          acc[m][n] = __builtin_amdgcn_mfma_f32_16x16x32_bf16(af[m][1], bfr[n][1], acc[m][n], 0, 0, 0);
        }
      __syncthreads();
    }

    float cn[4]; int ck[4];
#pragma unroll
    for (int n = 0; n < 4; ++n) { ck[n] = nbase + wc * 64 + n * 16 + c; cn[n] = Cnp[ck[n]]; }
#pragma unroll
    for (int m = 0; m < 4; ++m)
#pragma unroll
      for (int j = 0; j < 4; ++j) {
        float db = 3.4e38f, db2 = 3.4e38f; int di = 0;
#pragma unroll
        for (int n = 0; n < 4; ++n) {
          float d = __fmaf_rn(-2.0f, acc[m][n][j], cn[n]);
          if (d < db) { db2 = db; db = d; di = ck[n]; }
          else if (d < db2) db2 = d;
        }
#pragma unroll
        for (int off = 1; off < 16; off <<= 1) {
          float ob  = __shfl_xor(db, off, 64);
          float ob2 = __shfl_xor(db2, off, 64);
          int   oi  = __shfl_xor(di, off, 64);
          float lo = fminf(db, ob), hi = fmaxf(db, ob);
          db2 = fminf(fminf(db2, ob2), hi);
          di  = (ob < db || (ob == db && oi < di)) ? oi : di;
          db  = lo;
        }
        if (db < b1[m][j]) {
          b2v[m][j] = fminf(b1[m][j], db2);
          b1[m][j]  = db;
          bi[m][j]  = di;
        } else {
          b2v[m][j] = fminf(b2v[m][j], db);
        }
      }
  }

  // ---- cross-wave merge: each row is covered by waves (wr,0) and (wr,1) ----
  float* sB1 = (float*)tA;
  float* sB2 = sB1 + 128;
  int*   sBI = (int*)(sB2 + 128);
  __syncthreads();
  if (wc == 1 && c == 0) {
#pragma unroll
    for (int m = 0; m < 4; ++m)
#pragma unroll
      for (int j = 0; j < 4; ++j) {
        int r = wr * 64 + m * 16 + q * 4 + j;
        sB1[r] = b1[m][j]; sB2[r] = b2v[m][j]; sBI[r] = bi[m][j];
      }
  }
  __syncthreads();
  if (wc == 0 && c == 0) {
#pragma unroll
    for (int m = 0; m < 4; ++m)
#pragma unroll
      for (int j = 0; j < 4; ++j) {
        int r = wr * 64 + m * 16 + q * 4 + j;
        float o1 = sB1[r], o2 = sB2[r];
        int   oi = sBI[r];
        float best, sec; int bidx;
        if (o1 < b1[m][j] || (o1 == b1[m][j] && oi < bi[m][j])) {
          best = o1; bidx = oi; sec = fminf(o2, b1[m][j]);
        } else {
          best = b1[m][j]; bidx = bi[m][j]; sec = fminf(b2v[m][j], o1);
        }
        indices[mb + r] = bidx;
        if (sec - best < GAP_TAU) {
          int p = atomicAdd(flag_count, 1);
          if (p < MAX_FLAG) flagged[p] = mb + r;
        }
      }
  }
}

// ---------------- numpy-fp32-exact re-argmin, v2: coalesced wT reads ----------------
// Block = RB(16) rows; wave wv = rows wv*4..+3, lane kl, j=0..15 -> k = j*64+kl.
// B[r][j] is a strict d-ascending fp32 FMA chain (OpenBLAS microkernel semantics).
__global__ __launch_bounds__(256) void vq_refine_np2(
    const float* __restrict__ x, const float* __restrict__ wT,
    const float* __restrict__ Cnp, const int* __restrict__ flagged,
    const int* __restrict__ flag_count, int* __restrict__ indices) {
  __shared__ float xs[RB][D_EMB];
  __shared__ float Ash[RB];
  const int t = threadIdx.x;
  const int wv = t >> 6;
  const int kl = t & 63;
  const int r0 = wv * 4;
  int nf = *flag_count; if (nf > MAX_FLAG) nf = MAX_FLAG;
  int nblk = (nf + RB - 1) / RB;
  for (int bb = blockIdx.x; bb < nblk; bb += gridDim.x) {
    int base = bb * RB;
    int nr = nf - base; if (nr > RB) nr = RB;
    __syncthreads();
    {
      int r = t >> 4, p = t & 15;
      int src = flagged[base + (r < nr ? r : 0)];
      const float4* xp = (const float4*)(x + (size_t)src * D_EMB);
      float4* dst = (float4*)&xs[r][0];
#pragma unroll
      for (int i = 0; i < 4; ++i) dst[p + 16 * i] = xp[p + 16 * i];
    }
    __syncthreads();
    if (t < RB) Ash[t] = np_sumsq_256(xs[t]);
    __syncthreads();

    float B[4][16];
#pragma unroll
    for (int r = 0; r < 4; ++r)
#pragma unroll
      for (int j = 0; j < 16; ++j) B[r][j] = 0.f;

#pragma unroll 2
    for (int d = 0; d < D_EMB; ++d) {
      const float* wrow = wT + (size_t)d * K_CB + kl;
      float wv16[16];
#pragma unroll
      for (int j = 0; j < 16; ++j) wv16[j] = wrow[j * 64];
      float xv[4];
#pragma unroll
      for (int r = 0; r < 4; ++r) xv[r] = xs[r0 + r][d];
#pragma unroll
      for (int r = 0; r < 4; ++r)
#pragma unroll
        for (int j = 0; j < 16; ++j)
          B[r][j] = __fmaf_rn(xv[r], wv16[j], B[r][j]);
    }

    float cnv[16];
#pragma unroll
    for (int j = 0; j < 16; ++j) cnv[j] = Cnp[j * 64 + kl];

#pragma unroll
    for (int r = 0; r < 4; ++r) {
      float A = Ash[r0 + r];
      float bd = 3.4e38f; int bik = 0x7fffffff;
#pragma unroll
      for (int j = 0; j < 16; ++j) {       // j ascending => k ascending per lane
        float dq = __fadd_rn(__fsub_rn(A, __fmul_rn(2.0f, B[r][j])), cnv[j]);
        if (dq < bd) { bd = dq; bik = j * 64 + kl; }
      }
#pragma unroll
      for (int off = 1; off < 32; off <<= 1) {
        float od = __shfl_xor(bd, off, 64);
        int   ok = __shfl_xor(bik, off, 64);
        if (od < bd || (od == bd && ok < bik)) { bd = od; bik = ok; }
      }
      {
        float od = __shfl_xor(bd, 32, 64);
        int   ok = __shfl_xor(bik, 32, 64);
        if (od < bd || (od == bd && ok < bik)) { bd = od; bik = ok; }
      }
      if (kl == 0 && r0 + r < nr) indices[flagged[base + r0 + r]] = bik;
    }
  }
}

// ---------------- gather q, commitment loss partials, EMA scatter ----------------
__global__ __launch_bounds__(256) void vq_scatter(
    const float* __restrict__ x, const float* __restrict__ w,
    const int* __restrict__ indices, float* __restrict__ q_out,
    float* __restrict__ emb_sum, float* __restrict__ counts,
    float* __restrict__ loss_part, int M) {
  __shared__ float lsum[4];
  int wib  = threadIdx.x >> 6;
  int row  = blockIdx.x * 4 + wib;
  int lane = threadIdx.x & 63;
  float s = 0.0f;
  if (row < M) {
    int idx = indices[row];
    float4 xv = *(const float4*)(x + (size_t)row * D_EMB + lane * 4);
    float4 wv = *(const float4*)(w + (size_t)idx * D_EMB + lane * 4);
    float4 qs;
    qs.x = xv.x + (wv.x - xv.x);
    qs.y = xv.y + (wv.y - xv.y);
    qs.z = xv.z + (wv.z - xv.z);
    qs.w = xv.w + (wv.w - xv.w);
    *(float4*)(q_out + (size_t)row * D_EMB + lane * 4) = qs;
    float d0 = xv.x - wv.x, d1 = xv.y - wv.y, d2 = xv.z - wv.z, d3 = xv.w - wv.w;
    s = d0 * d0 + d1 * d1 + d2 * d2 + d3 * d3;
    float* es = emb_sum + (size_t)idx * D_EMB + lane * 4;
    atomicAdd(es + 0, xv.x);
    atomicAdd(es + 1, xv.y);
    atomicAdd(es + 2, xv.z);
    atomicAdd(es + 3, xv.w);
    if (lane == 0) atomicAdd(counts + idx, 1.0f);
  }
#pragma unroll
  for (int off = 32; off >= 1; off >>= 1) s += __shfl_xor(s, off, 64);
  if (lane == 0) lsum[wib] = s;
  __syncthreads();
  if (threadIdx.x == 0)
    loss_part[blockIdx.x] = lsum[0] + lsum[1] + lsum[2] + lsum[3];
}

// ---------------- cluster-size EMA, n, norm, loss ----------------
__global__ __launch_bounds__(1024) void vq_fin_cs(
    const float* __restrict__ ema_cs, const float* __restrict__ counts,
    const float* __restrict__ loss_part, int n_part, float inv_MD,
    float* __restrict__ out_ncs, float* __restrict__ out_loss,
    float* __restrict__ norm_inv) {
  __shared__ float sm[1024];
  __shared__ float sl[1024];
  int k = threadIdx.x;
  float ncs = ema_cs[k] * DECAY_F + counts[k] * OMD_F;
  out_ncs[k] = ncs;
  float ls = 0.f;
  for (int i = k; i < n_part; i += 1024) ls += loss_part[i];
  sm[k] = ncs; sl[k] = ls;
  __syncthreads();
  for (int s2 = 512; s2 > 0; s2 >>= 1) {
    if (k < s2) { sm[k] += sm[k + s2]; sl[k] += sl[k + s2]; }
    __syncthreads();
  }
  float n = sm[0];
  norm_inv[k] = (n + (float)K_CB * EPS_VQ) / (ncs + EPS_VQ);
  if (k == 0) out_loss[0] = sl[0] * inv_MD;
}

// ---------------- embedding EMA + new weight ----------------
__global__ __launch_bounds__(256) void vq_fin_w(
    const float* __restrict__ ema_emb, const float* __restrict__ emb_sum,
    const float* __restrict__ norm_inv, float* __restrict__ out_w,
    float* __restrict__ out_emb) {
  int e = blockIdx.x * 256 + threadIdx.x;
  float4 ee = ((const float4*)ema_emb)[e];
  float4 es = ((const float4*)emb_sum)[e];
  float4 ne;
  ne.x = ee.x * DECAY_F + es.x * OMD_F;
  ne.y = ee.y * DECAY_F + es.y * OMD_F;
  ne.z = ee.z * DECAY_F + es.z * OMD_F;
  ne.w = ee.w * DECAY_F + es.w * OMD_F;
  ((float4*)out_emb)[e] = ne;
  float ni = norm_inv[e >> 6];
  float4 nw;
  nw.x = ne.x * ni; nw.y = ne.y * ni; nw.z = ne.z * ni; nw.w = ne.w * ni;
  ((float4*)out_w)[e] = nw;
}

extern "C" void kernel_launch(void* const* d_in, const int* in_sizes, int n_in,
                              void* d_out, int out_size, void* d_ws, size_t ws_size,
                              hipStream_t stream) {
  const float* x       = (const float*)d_in[0];
  const float* w       = (const float*)d_in[1];
  const float* ema_cs  = (const float*)d_in[2];
  const float* ema_emb = (const float*)d_in[3];
  const int M = in_sizes[0] / D_EMB;   // 131072

  float* out      = (float*)d_out;
  float* out_q    = out;
  float* out_loss = out + (size_t)M * D_EMB;
  float* out_w    = out_loss + 1;
  float* out_ncs  = out_w + (size_t)K_CB * D_EMB;
  float* out_emb  = out_ncs + K_CB;

  float* ws         = (float*)d_ws;
  float* Cnp        = ws;                                      // 1024
  float* counts     = Cnp + K_CB;                              // 1024
  float* norm_inv   = counts + K_CB;                           // 1024
  float* emb_sum    = norm_inv + K_CB;                         // K*D
  int*   indices    = (int*)(emb_sum + (size_t)K_CB * D_EMB);  // M
  float* loss_part  = (float*)(indices + M);                   // M/4
  int*   flagged    = (int*)(loss_part + M / 4);               // MAX_FLAG
  int*   flag_count = flagged + MAX_FLAG;                      // 1 (+3 pad)
  unsigned short* w2 = (unsigned short*)(flag_count + 4);      // K*KDIM bf16 (1MB)
  float* wT         = (float*)(w2 + (size_t)K_CB * KDIM);      // K*K fp32 (4MB); ws total ~7MB

  unsigned short* x2 = (unsigned short*)out_q;  // bf16 split of x; rewritten by vq_scatter

  hipMemsetAsync(counts, 0, K_CB * sizeof(float), stream);
  hipMemsetAsync(emb_sum, 0, (size_t)K_CB * D_EMB * sizeof(float), stream);
  hipMemsetAsync(flag_count, 0, sizeof(int), stream);

  vq_split<<<M * 64 / 256, 256, 0, stream>>>(x, x2, M);
  vq_split<<<K_CB * 64 / 256, 256, 0, stream>>>(w, w2, K_CB);
  vq_transpose<<<64, 256, 0, stream>>>(w, wT);
  vq_wsq_np<<<K_CB / 256, 256, 0, stream>>>(w, Cnp);
  vq_gemm<<<M / 128, 256, 0, stream>>>(x2, w2, Cnp, indices, flagged, flag_count);
  vq_refine_np2<<<512, 256, 0, stream>>>(x, wT, Cnp, flagged, flag_count, indices);
  vq_scatter<<<M / 4, 256, 0, stream>>>(x, w, indices, out_q, emb_sum, counts,
                                        loss_part, M);
  vq_fin_cs<<<1, 1024, 0, stream>>>(ema_cs, counts, loss_part, M / 4,
                                    1.0f / ((float)M * (float)D_EMB),
                                    out_ncs, out_loss, norm_inv);
  vq_fin_w<<<K_CB * D_EMB / 4 / 256, 256, 0, stream>>>(ema_emb, emb_sum, norm_inv,
                                                       out_w, out_emb);
}

// Round 6
// 1302.094 us; speedup vs baseline: 6.0325x; 1.0011x over previous
//
#include <hip/hip_runtime.h>

#define K_CB 1024
#define D_EMB 256
#define KDIM 512                 // stored bf16-split K: [hi(256) | lo(256)]
#define DECAY_F 0.900009f
#define OMD_F 0.099991f
#define EPS_VQ 1e-5f
#define MAX_FLAG 65536
#define GAP_TAU 3e-4f
#define RB 16                    // flagged rows per refine block

typedef __bf16 bf16x8 __attribute__((ext_vector_type(8)));
typedef float f32x4 __attribute__((ext_vector_type(4)));

__device__ __forceinline__ unsigned short bf16rn(float f) {
  unsigned u = __float_as_uint(f);
  return (unsigned short)((u + 0x7fffu + ((u >> 16) & 1u)) >> 16);
}

#define STAGE16(srcp, dstp)                                                        \
  __builtin_amdgcn_global_load_lds(                                               \
      (const __attribute__((address_space(1))) unsigned int*)(srcp),              \
      (__attribute__((address_space(3))) unsigned int*)(dstp), 16, 0, 0)

// ---------------- fp32 -> bf16 hi/lo split: dst[row] = [hi(256) | lo(256)] ----------------
__global__ __launch_bounds__(256) void vq_split(const float* __restrict__ src,
                                                unsigned short* __restrict__ dst,
                                                int nrows) {
  int g = blockIdx.x * 256 + threadIdx.x;
  int row = g >> 6, d0 = (g & 63) << 2;
  if (row >= nrows) return;
  float4 v = *(const float4*)(src + (size_t)row * D_EMB + d0);
  ushort4 hi, lo;
  hi.x = bf16rn(v.x); lo.x = bf16rn(v.x - __uint_as_float((unsigned)hi.x << 16));
  hi.y = bf16rn(v.y); lo.y = bf16rn(v.y - __uint_as_float((unsigned)hi.y << 16));
  hi.z = bf16rn(v.z); lo.z = bf16rn(v.z - __uint_as_float((unsigned)hi.z << 16));
  hi.w = bf16rn(v.w); lo.w = bf16rn(v.w - __uint_as_float((unsigned)hi.w << 16));
  *(ushort4*)(dst + (size_t)row * KDIM + d0) = hi;
  *(ushort4*)(dst + (size_t)row * KDIM + D_EMB + d0) = lo;
}

// ---------------- w transpose: wT[d][k] = w[k][d] (for coalesced refine reads) ----------------
__global__ __launch_bounds__(256) void vq_transpose(const float* __restrict__ w,
                                                    float* __restrict__ wT) {
  __shared__ float tile[64][65];
  int bk = (blockIdx.x & 15) * 64;       // k block (K=1024 -> 16)
  int bd = (blockIdx.x >> 4) * 64;       // d block (D=256  -> 4)
  for (int i = threadIdx.x; i < 64 * 16; i += 256) {
    int kk = i >> 4, dd4 = (i & 15) * 4;
    float4 v = *(const float4*)(w + (size_t)(bk + kk) * D_EMB + bd + dd4);
    tile[kk][dd4]     = v.x; tile[kk][dd4 + 1] = v.y;
    tile[kk][dd4 + 2] = v.z; tile[kk][dd4 + 3] = v.w;
  }
  __syncthreads();
  for (int i = threadIdx.x; i < 64 * 64; i += 256) {
    int dd = i >> 6, kk = i & 63;
    wT[(size_t)(bd + dd) * K_CB + bk + kk] = tile[kk][dd];
  }
}

// ===== numpy float32 pairwise sum-of-squares emulation (exact) =====
__device__ __forceinline__ float np_block128_sq(const float* p) {
  float r[8];
#pragma unroll
  for (int j = 0; j < 8; ++j) r[j] = __fmul_rn(p[j], p[j]);
  for (int i = 8; i < 128; i += 8) {
#pragma unroll
    for (int j = 0; j < 8; ++j)
      r[j] = __fadd_rn(r[j], __fmul_rn(p[i + j], p[i + j]));
  }
  return __fadd_rn(__fadd_rn(__fadd_rn(r[0], r[1]), __fadd_rn(r[2], r[3])),
                   __fadd_rn(__fadd_rn(r[4], r[5]), __fadd_rn(r[6], r[7])));
}
__device__ __forceinline__ float np_sumsq_256(const float* p) {
  return __fadd_rn(np_block128_sq(p), np_block128_sq(p + 128));
}

__global__ __launch_bounds__(256) void vq_wsq_np(const float* __restrict__ w,
                                                 float* __restrict__ Cnp) {
  int k = blockIdx.x * 256 + threadIdx.x;
  if (k < K_CB) Cnp[k] = np_sumsq_256(w + (size_t)k * D_EMB);
}

// ---------------- MFMA screening GEMM + fused argmin(best/best2) ----------------
__global__ __launch_bounds__(256) void vq_gemm(
    const unsigned short* __restrict__ x2, const unsigned short* __restrict__ w2,
    const float* __restrict__ Cnp, int* __restrict__ indices,
    int* __restrict__ flagged, int* __restrict__ flag_count) {
  __shared__ unsigned short tA[128 * 64];
  __shared__ unsigned short tB[128 * 64];
  const int t = threadIdx.x;
  const int wid = t >> 6;
  const int wr = wid >> 1, wc = wid & 1;       // 2x2 wave grid, each 64(rows)x64(cols)
  const int lane = t & 63;
  const int q = lane >> 4, c = lane & 15;
  const int mb = blockIdx.x * 128;

  float b1[4][4], b2v[4][4];
  int   bi[4][4];
#pragma unroll
  for (int m = 0; m < 4; ++m)
#pragma unroll
    for (int j = 0; j < 4; ++j) { b1[m][j] = 3.4e38f; b2v[m][j] = 3.4e38f; bi[m][j] = 0; }

  for (int nt = 0; nt < 8; ++nt) {
    const int nbase = nt << 7;
    f32x4 acc[4][4];
#pragma unroll
    for (int m = 0; m < 4; ++m)
#pragma unroll
      for (int n = 0; n < 4; ++n) acc[m][n] = (f32x4){0.f, 0.f, 0.f, 0.f};

    const int AOFF[12] = {0, 64, 128, 192, 256, 320, 384, 448, 0, 64, 128, 192};
    const int BOFF[12] = {0, 64, 128, 192, 0, 64, 128, 192, 256, 320, 384, 448};
#pragma unroll
    for (int kc = 0; kc < 12; ++kc) {
#pragma unroll
      for (int cix = 0; cix < 4; ++cix) {
        int tp = (cix << 8) + t;
        int row = tp >> 3, sl = tp & 7;
        STAGE16(x2 + (size_t)(mb + row) * KDIM + AOFF[kc] + sl * 8, &tA[tp * 8]);
        STAGE16(w2 + (size_t)(nbase + row) * KDIM + BOFF[kc] + sl * 8, &tB[tp * 8]);
      }
      __syncthreads();
      bf16x8 af[4][2], bfr[4][2];
#pragma unroll
      for (int m = 0; m < 4; ++m)
#pragma unroll
        for (int ks = 0; ks < 2; ++ks) {
          af[m][ks]  = *(const bf16x8*)&tA[(wr * 64 + m * 16 + c) * 64 + ks * 32 + q * 8];
          bfr[m][ks] = *(const bf16x8*)&tB[(wc * 64 + m * 16 + c) * 64 + ks * 32 + q * 8];
        }
#pragma unroll
      for (int m = 0; m < 4; ++m)
#pragma unroll
        for (int n = 0; n < 4; ++n) {
          acc[m][n] = __builtin_amdgcn_mfma_f32_16x16x32_bf16(af[m][0], bfr[n][0], acc[m][n], 0, 0, 0);
          acc[m][n] = __builtin_amdgcn_mfma_f32_16x16x32_bf16(af[m][1], bfr[n][1], acc[m][n], 0, 0, 0);
        }
      __syncthreads();
    }

    float cn[4]; int ck[4];
#pragma unroll
    for (int n = 0; n < 4; ++n) { ck[n] = nbase + wc * 64 + n * 16 + c; cn[n] = Cnp[ck[n]]; }
#pragma unroll
    for (int m = 0; m < 4; ++m)
#pragma unroll
      for (int j = 0; j < 4; ++j) {
        float db = 3.4e38f, db2 = 3.4e38f; int di = 0;
#pragma unroll
        for (int n = 0; n < 4; ++n) {
          float d = __fmaf_rn(-2.0f, acc[m][n][j], cn[n]);
          if (d < db) { db2 = db; db = d; di = ck[n]; }
          else if (d < db2) db2 = d;
        }
#pragma unroll
        for (int off = 1; off < 16; off <<= 1) {
          float ob  = __shfl_xor(db, off, 64);
          float ob2 = __shfl_xor(db2, off, 64);
          int   oi  = __shfl_xor(di, off, 64);
          float lo = fminf(db, ob), hi = fmaxf(db, ob);
          db2 = fminf(fminf(db2, ob2), hi);
          di  = (ob < db || (ob == db && oi < di)) ? oi : di;
          db  = lo;
        }
        if (db < b1[m][j]) {
          b2v[m][j] = fminf(b1[m][j], db2);
          b1[m][j]  = db;
          bi[m][j]  = di;
        } else {
          b2v[m][j] = fminf(b2v[m][j], db);
        }
      }
  }

  // ---- cross-wave merge: each row is covered by waves (wr,0) and (wr,1) ----
  float* sB1 = (float*)tA;
  float* sB2 = sB1 + 128;
  int*   sBI = (int*)(sB2 + 128);
  __syncthreads();
  if (wc == 1 && c == 0) {
#pragma unroll
    for (int m = 0; m < 4; ++m)
#pragma unroll
      for (int j = 0; j < 4; ++j) {
        int r = wr * 64 + m * 16 + q * 4 + j;
        sB1[r] = b1[m][j]; sB2[r] = b2v[m][j]; sBI[r] = bi[m][j];
      }
  }
  __syncthreads();
  if (wc == 0 && c == 0) {
#pragma unroll
    for (int m = 0; m < 4; ++m)
#pragma unroll
      for (int j = 0; j < 4; ++j) {
        int r = wr * 64 + m * 16 + q * 4 + j;
        float o1 = sB1[r], o2 = sB2[r];
        int   oi = sBI[r];
        float best, sec; int bidx;
        if (o1 < b1[m][j] || (o1 == b1[m][j] && oi < bi[m][j])) {
          best = o1; bidx = oi; sec = fminf(o2, b1[m][j]);
        } else {
          best = b1[m][j]; bidx = bi[m][j]; sec = fminf(b2v[m][j], o1);
        }
        indices[mb + r] = bidx;
        if (sec - best < GAP_TAU) {
          int p = atomicAdd(flag_count, 1);
          if (p < MAX_FLAG) flagged[p] = mb + r;
        }
      }
  }
}

// ---------------- numpy-fp32-exact re-argmin, v2: coalesced wT reads ----------------
// Block = RB(16) rows; wave wv = rows wv*4..+3, lane kl, j=0..15 -> k = j*64+kl.
// B[r][j] is a strict d-ascending fp32 FMA chain (OpenBLAS microkernel semantics).
__global__ __launch_bounds__(256) void vq_refine_np2(
    const float* __restrict__ x, const float* __restrict__ wT,
    const float* __restrict__ Cnp, const int* __restrict__ flagged,
    const int* __restrict__ flag_count, int* __restrict__ indices) {
  __shared__ float xs[RB][D_EMB];
  __shared__ float Ash[RB];
  const int t = threadIdx.x;
  const int wv = t >> 6;
  const int kl = t & 63;
  const int r0 = wv * 4;
  int nf = *flag_count; if (nf > MAX_FLAG) nf = MAX_FLAG;
  int nblk = (nf + RB - 1) / RB;
  for (int bb = blockIdx.x; bb < nblk; bb += gridDim.x) {
    int base = bb * RB;
    int nr = nf - base; if (nr > RB) nr = RB;
    __syncthreads();
    {
      int r = t >> 4, p = t & 15;
      int src = flagged[base + (r < nr ? r : 0)];
      const float4* xp = (const float4*)(x + (size_t)src * D_EMB);
      float4* dst = (float4*)&xs[r][0];
#pragma unroll
      for (int i = 0; i < 4; ++i) dst[p + 16 * i] = xp[p + 16 * i];
    }
    __syncthreads();
    if (t < RB) Ash[t] = np_sumsq_256(xs[t]);
    __syncthreads();

    float B[4][16];
#pragma unroll
    for (int r = 0; r < 4; ++r)
#pragma unroll
      for (int j = 0; j < 16; ++j) B[r][j] = 0.f;

#pragma unroll 2
    for (int d = 0; d < D_EMB; ++d) {
      const float* wrow = wT + (size_t)d * K_CB + kl;
      float wv16[16];
#pragma unroll
      for (int j = 0; j < 16; ++j) wv16[j] = wrow[j * 64];
      float xv[4];
#pragma unroll
      for (int r = 0; r < 4; ++r) xv[r] = xs[r0 + r][d];
#pragma unroll
      for (int r = 0; r < 4; ++r)
#pragma unroll
        for (int j = 0; j < 16; ++j)
          B[r][j] = __fmaf_rn(xv[r], wv16[j], B[r][j]);
    }

    float cnv[16];
#pragma unroll
    for (int j = 0; j < 16; ++j) cnv[j] = Cnp[j * 64 + kl];

#pragma unroll
    for (int r = 0; r < 4; ++r) {
      float A = Ash[r0 + r];
      float bd = 3.4e38f; int bik = 0x7fffffff;
#pragma unroll
      for (int j = 0; j < 16; ++j) {       // j ascending => k ascending per lane
        float dq = __fadd_rn(__fsub_rn(A, __fmul_rn(2.0f, B[r][j])), cnv[j]);
        if (dq < bd) { bd = dq; bik = j * 64 + kl; }
      }
#pragma unroll
      for (int off = 1; off < 32; off <<= 1) {
        float od = __shfl_xor(bd, off, 64);
        int   ok = __shfl_xor(bik, off, 64);
        if (od < bd || (od == bd && ok < bik)) { bd = od; bik = ok; }
      }
      {
        float od = __shfl_xor(bd, 32, 64);
        int   ok = __shfl_xor(bik, 32, 64);
        if (od < bd || (od == bd && ok < bik)) { bd = od; bik = ok; }
      }
      if (kl == 0 && r0 + r < nr) indices[flagged[base + r0 + r]] = bik;
    }
  }
}

// ---------------- gather q, commitment loss partials, EMA scatter ----------------
__global__ __launch_bounds__(256) void vq_scatter(
    const float* __restrict__ x, const float* __restrict__ w,
    const int* __restrict__ indices, float* __restrict__ q_out,
    float* __restrict__ emb_sum, float* __restrict__ counts,
    float* __restrict__ loss_part, int M) {
  __shared__ float lsum[4];
  int wib  = threadIdx.x >> 6;
  int row  = blockIdx.x * 4 + wib;
  int lane = threadIdx.x & 63;
  float s = 0.0f;
  if (row < M) {
    int idx = indices[row];
    float4 xv = *(const float4*)(x + (size_t)row * D_EMB + lane * 4);
    float4 wv = *(const float4*)(w + (size_t)idx * D_EMB + lane * 4);
    float4 qs;
    qs.x = xv.x + (wv.x - xv.x);
    qs.y = xv.y + (wv.y - xv.y);
    qs.z = xv.z + (wv.z - xv.z);
    qs.w = xv.w + (wv.w - xv.w);
    *(float4*)(q_out + (size_t)row * D_EMB + lane * 4) = qs;
    float d0 = xv.x - wv.x, d1 = xv.y - wv.y, d2 = xv.z - wv.z, d3 = xv.w - wv.w;
    s = d0 * d0 + d1 * d1 + d2 * d2 + d3 * d3;
    float* es = emb_sum + (size_t)idx * D_EMB + lane * 4;
    atomicAdd(es + 0, xv.x);
    atomicAdd(es + 1, xv.y);
    atomicAdd(es + 2, xv.z);
    atomicAdd(es + 3, xv.w);
    if (lane == 0) atomicAdd(counts + idx, 1.0f);
  }
#pragma unroll
  for (int off = 32; off >= 1; off >>= 1) s += __shfl_xor(s, off, 64);
  if (lane == 0) lsum[wib] = s;
  __syncthreads();
  if (threadIdx.x == 0)
    loss_part[blockIdx.x] = lsum[0] + lsum[1] + lsum[2] + lsum[3];
}

// ---------------- cluster-size EMA, n, norm, loss ----------------
__global__ __launch_bounds__(1024) void vq_fin_cs(
    const float* __restrict__ ema_cs, const float* __restrict__ counts,
    const float* __restrict__ loss_part, int n_part, float inv_MD,
    float* __restrict__ out_ncs, float* __restrict__ out_loss,
    float* __restrict__ norm_inv) {
  __shared__ float sm[1024];
  __shared__ float sl[1024];
  int k = threadIdx.x;
  float ncs = ema_cs[k] * DECAY_F + counts[k] * OMD_F;
  out_ncs[k] = ncs;
  float ls = 0.f;
  for (int i = k; i < n_part; i += 1024) ls += loss_part[i];
  sm[k] = ncs; sl[k] = ls;
  __syncthreads();
  for (int s2 = 512; s2 > 0; s2 >>= 1) {
    if (k < s2) { sm[k] += sm[k + s2]; sl[k] += sl[k + s2]; }
    __syncthreads();
  }
  float n = sm[0];
  norm_inv[k] = (n + (float)K_CB * EPS_VQ) / (ncs + EPS_VQ);
  if (k == 0) out_loss[0] = sl[0] * inv_MD;
}

// ---------------- embedding EMA + new weight ----------------
__global__ __launch_bounds__(256) void vq_fin_w(
    const float* __restrict__ ema_emb, const float* __restrict__ emb_sum,
    const float* __restrict__ norm_inv, float* __restrict__ out_w,
    float* __restrict__ out_emb) {
  int e = blockIdx.x * 256 + threadIdx.x;
  float4 ee = ((const float4*)ema_emb)[e];
  float4 es = ((const float4*)emb_sum)[e];
  float4 ne;
  ne.x = ee.x * DECAY_F + es.x * OMD_F;
  ne.y = ee.y * DECAY_F + es.y * OMD_F;
  ne.z = ee.z * DECAY_F + es.z * OMD_F;
  ne.w = ee.w * DECAY_F + es.w * OMD_F;
  ((float4*)out_emb)[e] = ne;
  float ni = norm_inv[e >> 6];
  float4 nw;
  nw.x = ne.x * ni; nw.y = ne.y * ni; nw.z = ne.z * ni; nw.w = ne.w * ni;
  ((float4*)out_w)[e] = nw;
}

extern "C" void kernel_launch(void* const* d_in, const int* in_sizes, int n_in,
                              void* d_out, int out_size, void* d_ws, size_t ws_size,
                              hipStream_t stream) {
  const float* x       = (const float*)d_in[0];
  const float* w       = (const float*)d_in[1];
  const float* ema_cs  = (const float*)d_in[2];
  const float* ema_emb = (const float*)d_in[3];
  const int M = in_sizes[0] / D_EMB;   // 131072

  float* out      = (float*)d_out;
  float* out_q    = out;
  float* out_loss = out + (size_t)M * D_EMB;
  float* out_w    = out_loss + 1;
  float* out_ncs  = out_w + (size_t)K_CB * D_EMB;
  float* out_emb  = out_ncs + K_CB;

  float* ws         = (float*)d_ws;
  float* Cnp        = ws;                                      // 1024
  float* counts     = Cnp + K_CB;                              // 1024
  float* norm_inv   = counts + K_CB;                           // 1024
  float* emb_sum    = norm_inv + K_CB;                         // K*D
  int*   indices    = (int*)(emb_sum + (size_t)K_CB * D_EMB);  // M
  float* loss_part  = (float*)(indices + M);                   // M/4
  int*   flagged    = (int*)(loss_part + M / 4);               // MAX_FLAG
  int*   flag_count = flagged + MAX_FLAG;                      // 1 (+3 pad)
  unsigned short* w2 = (unsigned short*)(flag_count + 4);      // K*KDIM bf16 (1MB)
  float* wT         = (float*)(w2 + (size_t)K_CB * KDIM);      // K*K fp32 (4MB); ws total ~7MB

  unsigned short* x2 = (unsigned short*)out_q;  // bf16 split of x; rewritten by vq_scatter

  hipMemsetAsync(counts, 0, K_CB * sizeof(float), stream);
  hipMemsetAsync(emb_sum, 0, (size_t)K_CB * D_EMB * sizeof(float), stream);
  hipMemsetAsync(flag_count, 0, sizeof(int), stream);

  vq_split<<<M * 64 / 256, 256, 0, stream>>>(x, x2, M);
  vq_split<<<K_CB * 64 / 256, 256, 0, stream>>>(w, w2, K_CB);
  vq_transpose<<<64, 256, 0, stream>>>(w, wT);
  vq_wsq_np<<<K_CB / 256, 256, 0, stream>>>(w, Cnp);
  vq_gemm<<<M / 128, 256, 0, stream>>>(x2, w2, Cnp, indices, flagged, flag_count);
  vq_refine_np2<<<512, 256, 0, stream>>>(x, wT, Cnp, flagged, flag_count, indices);
  vq_scatter<<<M / 4, 256, 0, stream>>>(x, w, indices, out_q, emb_sum, counts,
                                        loss_part, M);
  vq_fin_cs<<<1, 1024, 0, stream>>>(ema_cs, counts, loss_part, M / 4,
                                    1.0f / ((float)M * (float)D_EMB),
                                    out_ncs, out_loss, norm_inv);
  vq_fin_w<<<K_CB * D_EMB / 4 / 256, 256, 0, stream>>>(ema_emb, emb_sum, norm_inv,
                                                       out_w, out_emb);
}